// Round 6
// baseline (228.662 us; speedup 1.0000x reference)
//
#include <hip/hip_runtime.h>
#include <math.h>

#define NF 50
#define REC 52   // per-block record: 50 z + s + pad
#define NBLK 1024
#define GRP_PER_BLK 32   // 512 threads = 32 groups of 16 lanes
#define LOG2E 1.44269504f

// All-lanes sum within each 16-lane DPP row via rotate butterfly.
__device__ __forceinline__ float row16_allsum(float v) {
    float t;
    t = __int_as_float(__builtin_amdgcn_update_dpp(0, __float_as_int(v), 0x121, 0xF, 0xF, true)); v += t; // row_ror:1
    t = __int_as_float(__builtin_amdgcn_update_dpp(0, __float_as_int(v), 0x122, 0xF, 0xF, true)); v += t; // row_ror:2
    t = __int_as_float(__builtin_amdgcn_update_dpp(0, __float_as_int(v), 0x124, 0xF, 0xF, true)); v += t; // row_ror:4
    t = __int_as_float(__builtin_amdgcn_update_dpp(0, __float_as_int(v), 0x128, 0xF, 0xF, true)); v += t; // row_ror:8
    return v;
}

// Per-lane partial of sum_f w_f / (e^{2 qW x_f} + 1)  (the r-part of w*tanh).
__device__ __forceinline__ float row_partial(float2 a, float2 b, float c2,
                                             float wA0, float wA1, float wB0, float wB1) {
    float r0 = __builtin_amdgcn_rcpf(__builtin_amdgcn_exp2f(c2 * a.x) + 1.f);
    float r1 = __builtin_amdgcn_rcpf(__builtin_amdgcn_exp2f(c2 * a.y) + 1.f);
    float r2 = __builtin_amdgcn_rcpf(__builtin_amdgcn_exp2f(c2 * b.x) + 1.f);
    float r3 = __builtin_amdgcn_rcpf(__builtin_amdgcn_exp2f(c2 * b.y) + 1.f);
    return fmaf(wA0, r0, fmaf(wA1, r1, fmaf(wB0, r2, wB1 * r3)));
}

// Fused single kernel: fixed-shift softmax-weighted accumulation + last-block
// finalize. score = sumW - 2*sum_f w_f/(e^{2qWx}+1); e = exp2(K - 2log2e*rowsum).
// 512 threads = 32 groups of 16 lanes; (512,8) forces <=64 VGPR so all
// NBLK blocks are resident (4 blocks/CU, 8 waves/SIMD).
__global__ __launch_bounds__(512, 8) void attn_fused(
    const float* __restrict__ query, const float* __restrict__ ql_w,
    const float* __restrict__ qWp, float* __restrict__ ws,
    int* __restrict__ counter, float* __restrict__ out,
    int T, int totalGroups, int nBlocks)
{
    const float qW = qWp[0];
    const int tid  = threadIdx.x;
    const int j    = tid & 15;
    const int gIn  = tid >> 4;
    const int gGlob = blockIdx.x * GRP_PER_BLK + gIn;
    const float2 zf2 = make_float2(0.f, 0.f);

    float wA0 = 0.f, wA1 = 0.f, wB0 = 0.f, wB1 = 0.f;
    if (j < 13) { wA0 = ql_w[2*j];     wA1 = ql_w[2*j+1]; }
    if (j < 12) { wB0 = ql_w[26+2*j];  wB1 = ql_w[27+2*j]; }

    const float sumAbsW = row16_allsum(fabsf(wA0)+fabsf(wA1)+fabsf(wB0)+fabsf(wB1));
    const float sumW    = row16_allsum(wA0 + wA1 + wB0 + wB1);
    const float M0 = (sumAbsW > 80.f) ? (sumAbsW - 80.f) : 0.f;  // overflow guard; 0 here
    const float c2 = 2.f * qW * LOG2E;
    const float K  = (sumW - M0) * LOG2E;
    const float n2l = -2.f * LOG2E;

    float s = 0.f, z0 = 0.f, z1 = 0.f, z2 = 0.f, z3 = 0.f;

    const int stride = totalGroups;
    const int nq = T / (4 * stride);      // quads where ALL groups' 4 rows < T
    int row = gGlob;

    for (int q = 0; q < nq; ++q, row += 4*stride) {
        const float2* q0_ = (const float2*)(query + (size_t)row * NF);
        const float2* q1_ = (const float2*)(query + (size_t)(row +   stride) * NF);
        const float2* q2_ = (const float2*)(query + (size_t)(row + 2*stride) * NF);
        const float2* q3_ = (const float2*)(query + (size_t)(row + 3*stride) * NF);
        float2 a0=zf2,b0=zf2,a1=zf2,b1=zf2,a2=zf2,b2=zf2,a3=zf2,b3=zf2;
        if (j < 13) { a0 = q0_[j];    a1 = q1_[j];    a2 = q2_[j];    a3 = q3_[j]; }
        if (j < 12) { b0 = q0_[13+j]; b1 = q1_[13+j]; b2 = q2_[13+j]; b3 = q3_[13+j]; }

        float p0 = row16_allsum(row_partial(a0, b0, c2, wA0, wA1, wB0, wB1));
        float p1 = row16_allsum(row_partial(a1, b1, c2, wA0, wA1, wB0, wB1));
        float p2 = row16_allsum(row_partial(a2, b2, c2, wA0, wA1, wB0, wB1));
        float p3 = row16_allsum(row_partial(a3, b3, c2, wA0, wA1, wB0, wB1));
        float e0 = __builtin_amdgcn_exp2f(fmaf(p0, n2l, K));
        float e1 = __builtin_amdgcn_exp2f(fmaf(p1, n2l, K));
        float e2 = __builtin_amdgcn_exp2f(fmaf(p2, n2l, K));
        float e3 = __builtin_amdgcn_exp2f(fmaf(p3, n2l, K));

        s += (e0 + e1) + (e2 + e3);
        z0 = fmaf(e0, a0.x, fmaf(e1, a1.x, fmaf(e2, a2.x, fmaf(e3, a3.x, z0))));
        z1 = fmaf(e0, a0.y, fmaf(e1, a1.y, fmaf(e2, a2.y, fmaf(e3, a3.y, z1))));
        z2 = fmaf(e0, b0.x, fmaf(e1, b1.x, fmaf(e2, b2.x, fmaf(e3, b3.x, z2))));
        z3 = fmaf(e0, b0.y, fmaf(e1, b1.y, fmaf(e2, b2.y, fmaf(e3, b3.y, z3))));
    }

    // One masked quad covers all remaining rows (remaining < 4*stride).
    if (row < T) {
        const int r1 = row + stride, r2 = row + 2*stride, r3 = row + 3*stride;
        const bool v1 = r1 < T, v2 = r2 < T, v3 = r3 < T;
        const float2* q0_ = (const float2*)(query + (size_t)row * NF);
        const float2* q1_ = (const float2*)(query + (size_t)r1 * NF);
        const float2* q2_ = (const float2*)(query + (size_t)r2 * NF);
        const float2* q3_ = (const float2*)(query + (size_t)r3 * NF);
        float2 a0=zf2,b0=zf2,a1=zf2,b1=zf2,a2=zf2,b2=zf2,a3=zf2,b3=zf2;
        if (j < 13)       { a0 = q0_[j]; }
        if (j < 12)       { b0 = q0_[13+j]; }
        if (j < 13 && v1) { a1 = q1_[j]; }
        if (j < 12 && v1) { b1 = q1_[13+j]; }
        if (j < 13 && v2) { a2 = q2_[j]; }
        if (j < 12 && v2) { b2 = q2_[13+j]; }
        if (j < 13 && v3) { a3 = q3_[j]; }
        if (j < 12 && v3) { b3 = q3_[13+j]; }

        float p0 = row16_allsum(row_partial(a0, b0, c2, wA0, wA1, wB0, wB1));
        float p1 = row16_allsum(row_partial(a1, b1, c2, wA0, wA1, wB0, wB1));
        float p2 = row16_allsum(row_partial(a2, b2, c2, wA0, wA1, wB0, wB1));
        float p3 = row16_allsum(row_partial(a3, b3, c2, wA0, wA1, wB0, wB1));
        float e0 =      __builtin_amdgcn_exp2f(fmaf(p0, n2l, K));
        float e1 = v1 ? __builtin_amdgcn_exp2f(fmaf(p1, n2l, K)) : 0.f;
        float e2 = v2 ? __builtin_amdgcn_exp2f(fmaf(p2, n2l, K)) : 0.f;
        float e3 = v3 ? __builtin_amdgcn_exp2f(fmaf(p3, n2l, K)) : 0.f;

        s += (e0 + e1) + (e2 + e3);
        z0 = fmaf(e0, a0.x, fmaf(e1, a1.x, fmaf(e2, a2.x, fmaf(e3, a3.x, z0))));
        z1 = fmaf(e0, a0.y, fmaf(e1, a1.y, fmaf(e2, a2.y, fmaf(e3, a3.y, z1))));
        z2 = fmaf(e0, b0.x, fmaf(e1, b1.x, fmaf(e2, b2.x, fmaf(e3, b3.x, z2))));
        z3 = fmaf(e0, b0.y, fmaf(e1, b1.y, fmaf(e2, b2.y, fmaf(e3, b3.y, z3))));
    }

    // Per-block LDS merge -> record
    __shared__ float sz[GRP_PER_BLK][REC];
    __shared__ int isLast;
    if (j < 13) { sz[gIn][2*j]    = z0; sz[gIn][2*j+1]  = z1; }
    if (j < 12) { sz[gIn][26+2*j] = z2; sz[gIn][27+2*j] = z3; }
    if (j == 13) { sz[gIn][50] = s; sz[gIn][51] = 0.f; }
    __syncthreads();

    if (tid < 51) {
        float acc = 0.f;
        #pragma unroll
        for (int h = 0; h < GRP_PER_BLK; ++h) acc += sz[h][tid];
        ws[(size_t)blockIdx.x * REC + tid] = acc;
    }
    __threadfence();
    __syncthreads();
    if (tid == 0) {
        int old = __hip_atomic_fetch_add(counter, 1, __ATOMIC_ACQ_REL,
                                         __HIP_MEMORY_SCOPE_AGENT);
        isLast = (old == nBlocks - 1);
    }
    __syncthreads();

    if (isLast) {
        __threadfence();  // acquire: make all records visible
        const int w = tid >> 6, lane = tid & 63;   // 8 waves
        float acc = 0.f;
        if (lane < 51) {
            int b = w;
            for (; b + 24 < nBlocks; b += 32) {
                acc += ws[(size_t)(b     ) * REC + lane]
                     + ws[(size_t)(b +  8) * REC + lane]
                     + ws[(size_t)(b + 16) * REC + lane]
                     + ws[(size_t)(b + 24) * REC + lane];
            }
            for (; b < nBlocks; b += 8)
                acc += ws[(size_t)b * REC + lane];
            sz[w][lane] = acc;
        }
        __syncthreads();
        if (tid < NF) {
            float Z = 0.f, S = 0.f;
            #pragma unroll
            for (int h = 0; h < 8; ++h) { Z += sz[h][tid]; S += sz[h][50]; }
            out[tid] = Z / S;
        }
    }
}

extern "C" void kernel_launch(void* const* d_in, const int* in_sizes, int n_in,
                              void* d_out, int out_size, void* d_ws, size_t ws_size,
                              hipStream_t stream) {
    const float* query = (const float*)d_in[0];
    const float* ql_w  = (const float*)d_in[1];
    const float* qW    = (const float*)d_in[2];
    float* out = (float*)d_out;
    float* ws  = (float*)d_ws;

    const int T = in_sizes[0] / NF;

    int B = NBLK;
    size_t need = (size_t)B * REC * sizeof(float) + sizeof(int);
    if (ws_size < need) {
        B = (int)((ws_size - sizeof(int)) / (REC * sizeof(float)));
        if (B < 1) B = 1;
    }

    int* counter = (int*)(ws + (size_t)B * REC);
    hipMemsetAsync(counter, 0, sizeof(int), stream);

    const int totalGroups = B * GRP_PER_BLK;
    hipLaunchKernelGGL(attn_fused, dim3(B), dim3(512), 0, stream,
                       query, ql_w, qW, ws, counter, out, T, totalGroups, B);
}

// Round 7
// 28.334 us; speedup vs baseline: 8.0701x; 8.0701x over previous
//
#include <hip/hip_runtime.h>
#include <math.h>

#define NF 50
#define REC 52   // per-block record: 50 z + s + pad
#define NBLK 1024
#define GRP_PER_BLK 32   // 512 threads = 32 groups of 16 lanes
#define LOG2E 1.44269504f

// All-lanes sum within each 16-lane DPP row via rotate butterfly.
__device__ __forceinline__ float row16_allsum(float v) {
    float t;
    t = __int_as_float(__builtin_amdgcn_update_dpp(0, __float_as_int(v), 0x121, 0xF, 0xF, true)); v += t; // row_ror:1
    t = __int_as_float(__builtin_amdgcn_update_dpp(0, __float_as_int(v), 0x122, 0xF, 0xF, true)); v += t; // row_ror:2
    t = __int_as_float(__builtin_amdgcn_update_dpp(0, __float_as_int(v), 0x124, 0xF, 0xF, true)); v += t; // row_ror:4
    t = __int_as_float(__builtin_amdgcn_update_dpp(0, __float_as_int(v), 0x128, 0xF, 0xF, true)); v += t; // row_ror:8
    return v;
}

// Per-lane partial of sum_f w_f / (e^{2 qW x_f} + 1)  (the r-part of w*tanh).
__device__ __forceinline__ float row_partial(float2 a, float2 b, float c2,
                                             float wA0, float wA1, float wB0, float wB1) {
    float r0 = __builtin_amdgcn_rcpf(__builtin_amdgcn_exp2f(c2 * a.x) + 1.f);
    float r1 = __builtin_amdgcn_rcpf(__builtin_amdgcn_exp2f(c2 * a.y) + 1.f);
    float r2 = __builtin_amdgcn_rcpf(__builtin_amdgcn_exp2f(c2 * b.x) + 1.f);
    float r3 = __builtin_amdgcn_rcpf(__builtin_amdgcn_exp2f(c2 * b.y) + 1.f);
    return fmaf(wA0, r0, fmaf(wA1, r1, fmaf(wB0, r2, wB1 * r3)));
}

// Pass 1: fixed-shift softmax-weighted accumulation (R4 structure).
// score = sumW - 2*sum_f w_f/(e^{2qWx}+1); e = exp2(K - 2log2e*rowsum).
// 512 threads = 32 groups of 16 lanes; (512,8) -> <=64 VGPR, all blocks
// resident. Tail handled by ONE clamped-index masked quad: loads always
// execute (indices clamped to T-1), only the e-weights are zeroed, so the
// register shape matches the main loop (no spill-inducing liveness).
__global__ __launch_bounds__(512, 8) void attn_pass1(
    const float* __restrict__ query, const float* __restrict__ ql_w,
    const float* __restrict__ qWp, float* __restrict__ ws,
    int T, int totalGroups)
{
    const float qW = qWp[0];
    const int tid  = threadIdx.x;
    const int j    = tid & 15;
    const int gIn  = tid >> 4;
    const int gGlob = blockIdx.x * GRP_PER_BLK + gIn;
    const float2 zf2 = make_float2(0.f, 0.f);

    float wA0 = 0.f, wA1 = 0.f, wB0 = 0.f, wB1 = 0.f;
    if (j < 13) { wA0 = ql_w[2*j];     wA1 = ql_w[2*j+1]; }
    if (j < 12) { wB0 = ql_w[26+2*j];  wB1 = ql_w[27+2*j]; }

    const float sumAbsW = row16_allsum(fabsf(wA0)+fabsf(wA1)+fabsf(wB0)+fabsf(wB1));
    const float sumW    = row16_allsum(wA0 + wA1 + wB0 + wB1);
    const float M0 = (sumAbsW > 80.f) ? (sumAbsW - 80.f) : 0.f;  // overflow guard; 0 here
    const float c2 = 2.f * qW * LOG2E;
    const float K  = (sumW - M0) * LOG2E;
    const float n2l = -2.f * LOG2E;

    float s = 0.f, z0 = 0.f, z1 = 0.f, z2 = 0.f, z3 = 0.f;

    const int stride = totalGroups;
    int row = gGlob;

    for (; row + 3*stride < T; row += 4*stride) {
        const float2* q0_ = (const float2*)(query + (size_t)row * NF);
        const float2* q1_ = (const float2*)(query + (size_t)(row +   stride) * NF);
        const float2* q2_ = (const float2*)(query + (size_t)(row + 2*stride) * NF);
        const float2* q3_ = (const float2*)(query + (size_t)(row + 3*stride) * NF);
        float2 a0=zf2,b0=zf2,a1=zf2,b1=zf2,a2=zf2,b2=zf2,a3=zf2,b3=zf2;
        if (j < 13) { a0 = q0_[j];    a1 = q1_[j];    a2 = q2_[j];    a3 = q3_[j]; }
        if (j < 12) { b0 = q0_[13+j]; b1 = q1_[13+j]; b2 = q2_[13+j]; b3 = q3_[13+j]; }

        float p0 = row16_allsum(row_partial(a0, b0, c2, wA0, wA1, wB0, wB1));
        float p1 = row16_allsum(row_partial(a1, b1, c2, wA0, wA1, wB0, wB1));
        float p2 = row16_allsum(row_partial(a2, b2, c2, wA0, wA1, wB0, wB1));
        float p3 = row16_allsum(row_partial(a3, b3, c2, wA0, wA1, wB0, wB1));
        float e0 = __builtin_amdgcn_exp2f(fmaf(p0, n2l, K));
        float e1 = __builtin_amdgcn_exp2f(fmaf(p1, n2l, K));
        float e2 = __builtin_amdgcn_exp2f(fmaf(p2, n2l, K));
        float e3 = __builtin_amdgcn_exp2f(fmaf(p3, n2l, K));

        s += (e0 + e1) + (e2 + e3);
        z0 = fmaf(e0, a0.x, fmaf(e1, a1.x, fmaf(e2, a2.x, fmaf(e3, a3.x, z0))));
        z1 = fmaf(e0, a0.y, fmaf(e1, a1.y, fmaf(e2, a2.y, fmaf(e3, a3.y, z1))));
        z2 = fmaf(e0, b0.x, fmaf(e1, b1.x, fmaf(e2, b2.x, fmaf(e3, b3.x, z2))));
        z3 = fmaf(e0, b0.y, fmaf(e1, b1.y, fmaf(e2, b2.y, fmaf(e3, b3.y, z3))));
    }

    if (row < T) {
        // Clamped masked quad: all loads execute with safe indices.
        const int r1 = row + stride, r2 = row + 2*stride, r3 = row + 3*stride;
        const int c1 = (r1 < T) ? r1 : (T - 1);
        const int cc2 = (r2 < T) ? r2 : (T - 1);
        const int c3 = (r3 < T) ? r3 : (T - 1);
        const float2* q0_ = (const float2*)(query + (size_t)row * NF);
        const float2* q1_ = (const float2*)(query + (size_t)c1 * NF);
        const float2* q2_ = (const float2*)(query + (size_t)cc2 * NF);
        const float2* q3_ = (const float2*)(query + (size_t)c3 * NF);
        float2 a0=zf2,b0=zf2,a1=zf2,b1=zf2,a2=zf2,b2=zf2,a3=zf2,b3=zf2;
        if (j < 13) { a0 = q0_[j];    a1 = q1_[j];    a2 = q2_[j];    a3 = q3_[j]; }
        if (j < 12) { b0 = q0_[13+j]; b1 = q1_[13+j]; b2 = q2_[13+j]; b3 = q3_[13+j]; }

        float p0 = row16_allsum(row_partial(a0, b0, c2, wA0, wA1, wB0, wB1));
        float p1 = row16_allsum(row_partial(a1, b1, c2, wA0, wA1, wB0, wB1));
        float p2 = row16_allsum(row_partial(a2, b2, c2, wA0, wA1, wB0, wB1));
        float p3 = row16_allsum(row_partial(a3, b3, c2, wA0, wA1, wB0, wB1));
        float e0 = __builtin_amdgcn_exp2f(fmaf(p0, n2l, K));
        float e1 = (r1 < T) ? __builtin_amdgcn_exp2f(fmaf(p1, n2l, K)) : 0.f;
        float e2 = (r2 < T) ? __builtin_amdgcn_exp2f(fmaf(p2, n2l, K)) : 0.f;
        float e3 = (r3 < T) ? __builtin_amdgcn_exp2f(fmaf(p3, n2l, K)) : 0.f;

        s += (e0 + e1) + (e2 + e3);
        z0 = fmaf(e0, a0.x, fmaf(e1, a1.x, fmaf(e2, a2.x, fmaf(e3, a3.x, z0))));
        z1 = fmaf(e0, a0.y, fmaf(e1, a1.y, fmaf(e2, a2.y, fmaf(e3, a3.y, z1))));
        z2 = fmaf(e0, b0.x, fmaf(e1, b1.x, fmaf(e2, b2.x, fmaf(e3, b3.x, z2))));
        z3 = fmaf(e0, b0.y, fmaf(e1, b1.y, fmaf(e2, b2.y, fmaf(e3, b3.y, z3))));
    }

    __shared__ float sz[GRP_PER_BLK][REC];
    if (j < 13) { sz[gIn][2*j]    = z0; sz[gIn][2*j+1]  = z1; }
    if (j < 12) { sz[gIn][26+2*j] = z2; sz[gIn][27+2*j] = z3; }
    if (j == 13) { sz[gIn][50] = s; sz[gIn][51] = 0.f; }
    __syncthreads();

    // per-block record = plain sum over the 32 groups (same shift everywhere)
    if (tid < 51) {
        float acc = 0.f;
        #pragma unroll
        for (int h = 0; h < GRP_PER_BLK; ++h) acc += sz[h][tid];
        ws[(size_t)blockIdx.x * REC + tid] = acc;
    }
}

// Pass 2: plain sum of B records (50 z + s each), divide, store.
__global__ __launch_bounds__(1024) void attn_pass2(
    const float* __restrict__ ws, float* __restrict__ out, int B)
{
    __shared__ float zacc[16][REC];
    const int tid = threadIdx.x;
    const int w = tid >> 6, lane = tid & 63;

    if (lane < 51) {
        float acc = 0.f;
        int b = w;
        for (; b + 112 < B; b += 128) {
            acc += ws[(size_t)(b      ) * REC + lane]
                 + ws[(size_t)(b +  16) * REC + lane]
                 + ws[(size_t)(b +  32) * REC + lane]
                 + ws[(size_t)(b +  48) * REC + lane]
                 + ws[(size_t)(b +  64) * REC + lane]
                 + ws[(size_t)(b +  80) * REC + lane]
                 + ws[(size_t)(b +  96) * REC + lane]
                 + ws[(size_t)(b + 112) * REC + lane];
        }
        for (; b < B; b += 16)
            acc += ws[(size_t)b * REC + lane];
        zacc[w][lane] = acc;
    }
    __syncthreads();
    if (tid < NF) {
        float Z = 0.f, S = 0.f;
        #pragma unroll
        for (int h = 0; h < 16; ++h) { Z += zacc[h][tid]; S += zacc[h][50]; }
        out[tid] = Z / S;
    }
}

extern "C" void kernel_launch(void* const* d_in, const int* in_sizes, int n_in,
                              void* d_out, int out_size, void* d_ws, size_t ws_size,
                              hipStream_t stream) {
    const float* query = (const float*)d_in[0];
    const float* ql_w  = (const float*)d_in[1];
    const float* qW    = (const float*)d_in[2];
    float* out = (float*)d_out;
    float* ws  = (float*)d_ws;

    const int T = in_sizes[0] / NF;

    int B = NBLK;
    size_t need = (size_t)B * REC * sizeof(float);
    if (ws_size < need) {
        B = (int)(ws_size / (REC * sizeof(float)));
        if (B < 1) B = 1;
    }

    const int totalGroups = B * GRP_PER_BLK;
    hipLaunchKernelGGL(attn_pass1, dim3(B), dim3(512), 0, stream,
                       query, ql_w, qW, ws, T, totalGroups);
    hipLaunchKernelGGL(attn_pass2, dim3(1), dim3(1024), 0, stream,
                       ws, out, B);
}

// Round 8
// 25.709 us; speedup vs baseline: 8.8944x; 1.1021x over previous
//
#include <hip/hip_runtime.h>
#include <math.h>

#define NF 50
#define REC 52           // per-block record: 50 z + s + pad
#define NBLK 512         // pass1 grid
#define LOG2E 1.44269504f

// DPP ctrl codes
#define DPP_QXOR1 0xB1   // quad_perm [1,0,3,2]
#define DPP_QXOR2 0x4E   // quad_perm [2,3,0,1]
#define DPP_ROR4  0x124  // row_ror:4
#define DPP_ROR8  0x128  // row_ror:8

__device__ __forceinline__ float dpp_add(float v, int ctrl) {
    float t;
    switch (ctrl) {  // ctrl must be an ICE for the builtin
      case DPP_QXOR1: t = __int_as_float(__builtin_amdgcn_update_dpp(0, __float_as_int(v), DPP_QXOR1, 0xF, 0xF, true)); break;
      case DPP_QXOR2: t = __int_as_float(__builtin_amdgcn_update_dpp(0, __float_as_int(v), DPP_QXOR2, 0xF, 0xF, true)); break;
      case DPP_ROR4:  t = __int_as_float(__builtin_amdgcn_update_dpp(0, __float_as_int(v), DPP_ROR4,  0xF, 0xF, true)); break;
      default:        t = __int_as_float(__builtin_amdgcn_update_dpp(0, __float_as_int(v), DPP_ROR8,  0xF, 0xF, true)); break;
    }
    return v + t;
}

// Pass 1: one hardware quad (4 lanes) per row. Lane q owns float2 slots
// q+4t (t=0..5) plus a 7th slot (real slot 24 for q==0; duplicate of t=5
// with zero weight for q!=0 -> contributes nothing, keeps shape uniform).
// score = sumW - 2*sum_f w_f/(e^{2qWx}+1); e = exp2(K - 2log2e * p).
// Quad reduce = 2 DPP quad_perm ops. z per-lane in regs (features disjoint
// across lanes); epilogue: ror4+ror8 sums the 4 quads of each 16-lane row.
// 512 blocks x 512 thr = 2 blocks/CU, all resident; (512,4) -> <=128 VGPR.
__global__ __launch_bounds__(512, 4) void attn_pass1(
    const float* __restrict__ query, const float* __restrict__ ql_w,
    const float* __restrict__ qWp, float* __restrict__ ws,
    int T, int totalGroups)
{
    const float qW = qWp[0];
    const int tid = threadIdx.x;
    const int q   = tid & 3;                       // lane within quad
    const int g   = blockIdx.x * 128 + (tid >> 2); // global group id (row stream)

    // per-lane weights for slots q+4t
    float2 w01[7];
    #pragma unroll
    for (int t = 0; t < 6; ++t) {
        const int s = q + 4 * t;
        w01[t] = *(const float2*)(ql_w + 2 * s);
    }
    w01[6] = (q == 0) ? *(const float2*)(ql_w + 48) : make_float2(0.f, 0.f);
    const int d6 = (q == 0) ? 192 : 160;           // 7th-slot byte offset from rp

    // sumW / sumAbsW: per-lane partial over its slots, then quad reduce.
    float sw = 0.f, saw = 0.f;
    #pragma unroll
    for (int t = 0; t < 7; ++t) {
        sw  += w01[t].x + w01[t].y;
        saw += fabsf(w01[t].x) + fabsf(w01[t].y);
    }
    sw  = dpp_add(dpp_add(sw,  DPP_QXOR1), DPP_QXOR2);
    saw = dpp_add(dpp_add(saw, DPP_QXOR1), DPP_QXOR2);
    const float M0  = (saw > 80.f) ? (saw - 80.f) : 0.f;   // overflow guard; 0 here
    const float c2  = 2.f * qW * LOG2E;
    const float K   = (sw - M0) * LOG2E;
    const float n2l = -2.f * LOG2E;

    float2 z[7];
    #pragma unroll
    for (int t = 0; t < 7; ++t) z[t] = make_float2(0.f, 0.f);
    float se = 0.f;

    const int G = totalGroups;                     // NBLK*128 = 65536
    const char* rp = (const char*)(query + (size_t)g * NF) + (q << 3);
    const size_t step = (size_t)G * NF * sizeof(float);

    for (int row = g; row < T; row += G, rp += step) {
        float2 x0 = *(const float2*)(rp);
        float2 x1 = *(const float2*)(rp + 32);
        float2 x2 = *(const float2*)(rp + 64);
        float2 x3 = *(const float2*)(rp + 96);
        float2 x4 = *(const float2*)(rp + 128);
        float2 x5 = *(const float2*)(rp + 160);
        float2 x6 = *(const float2*)(rp + d6);

        float p = 0.f;
        {
            float r;
            r = __builtin_amdgcn_rcpf(__builtin_amdgcn_exp2f(c2 * x0.x) + 1.f); p = fmaf(w01[0].x, r, p);
            r = __builtin_amdgcn_rcpf(__builtin_amdgcn_exp2f(c2 * x0.y) + 1.f); p = fmaf(w01[0].y, r, p);
            r = __builtin_amdgcn_rcpf(__builtin_amdgcn_exp2f(c2 * x1.x) + 1.f); p = fmaf(w01[1].x, r, p);
            r = __builtin_amdgcn_rcpf(__builtin_amdgcn_exp2f(c2 * x1.y) + 1.f); p = fmaf(w01[1].y, r, p);
            r = __builtin_amdgcn_rcpf(__builtin_amdgcn_exp2f(c2 * x2.x) + 1.f); p = fmaf(w01[2].x, r, p);
            r = __builtin_amdgcn_rcpf(__builtin_amdgcn_exp2f(c2 * x2.y) + 1.f); p = fmaf(w01[2].y, r, p);
            r = __builtin_amdgcn_rcpf(__builtin_amdgcn_exp2f(c2 * x3.x) + 1.f); p = fmaf(w01[3].x, r, p);
            r = __builtin_amdgcn_rcpf(__builtin_amdgcn_exp2f(c2 * x3.y) + 1.f); p = fmaf(w01[3].y, r, p);
            r = __builtin_amdgcn_rcpf(__builtin_amdgcn_exp2f(c2 * x4.x) + 1.f); p = fmaf(w01[4].x, r, p);
            r = __builtin_amdgcn_rcpf(__builtin_amdgcn_exp2f(c2 * x4.y) + 1.f); p = fmaf(w01[4].y, r, p);
            r = __builtin_amdgcn_rcpf(__builtin_amdgcn_exp2f(c2 * x5.x) + 1.f); p = fmaf(w01[5].x, r, p);
            r = __builtin_amdgcn_rcpf(__builtin_amdgcn_exp2f(c2 * x5.y) + 1.f); p = fmaf(w01[5].y, r, p);
            r = __builtin_amdgcn_rcpf(__builtin_amdgcn_exp2f(c2 * x6.x) + 1.f); p = fmaf(w01[6].x, r, p);
            r = __builtin_amdgcn_rcpf(__builtin_amdgcn_exp2f(c2 * x6.y) + 1.f); p = fmaf(w01[6].y, r, p);
        }
        p = dpp_add(dpp_add(p, DPP_QXOR1), DPP_QXOR2);  // full 50-feature sum
        const float e = __builtin_amdgcn_exp2f(fmaf(p, n2l, K));

        se += e;
        z[0].x = fmaf(e, x0.x, z[0].x); z[0].y = fmaf(e, x0.y, z[0].y);
        z[1].x = fmaf(e, x1.x, z[1].x); z[1].y = fmaf(e, x1.y, z[1].y);
        z[2].x = fmaf(e, x2.x, z[2].x); z[2].y = fmaf(e, x2.y, z[2].y);
        z[3].x = fmaf(e, x3.x, z[3].x); z[3].y = fmaf(e, x3.y, z[3].y);
        z[4].x = fmaf(e, x4.x, z[4].x); z[4].y = fmaf(e, x4.y, z[4].y);
        z[5].x = fmaf(e, x5.x, z[5].x); z[5].y = fmaf(e, x5.y, z[5].y);
        z[6].x = fmaf(e, x6.x, z[6].x); z[6].y = fmaf(e, x6.y, z[6].y);
    }

    // Sum the 4 quads within each 16-lane row (lanes l, l+4, l+8, l+12
    // share q and hold disjoint rows' partials for the same slots).
    #pragma unroll
    for (int t = 0; t < 7; ++t) {
        z[t].x = dpp_add(dpp_add(z[t].x, DPP_ROR4), DPP_ROR8);
        z[t].y = dpp_add(dpp_add(z[t].y, DPP_ROR4), DPP_ROR8);
    }
    se = dpp_add(dpp_add(se, DPP_ROR4), DPP_ROR8);

    __shared__ float sz[32][REC];
    if ((tid & 15) < 4) {                  // one writer per q per 16-row
        const int eidx = tid >> 4;         // 0..31
        #pragma unroll
        for (int t = 0; t < 6; ++t) {
            const int s = q + 4 * t;
            *(float2*)&sz[eidx][2 * s] = z[t];
        }
        if (q == 0) {
            *(float2*)&sz[eidx][48] = z[6];
            sz[eidx][50] = se;
            sz[eidx][51] = 0.f;
        }
    }
    __syncthreads();

    if (tid < 51) {
        float acc = 0.f;
        #pragma unroll
        for (int h = 0; h < 32; ++h) acc += sz[h][tid];
        ws[(size_t)blockIdx.x * REC + tid] = acc;
    }
}

// Pass 2: plain sum of B records (50 z + s each), divide, store.
__global__ __launch_bounds__(1024) void attn_pass2(
    const float* __restrict__ ws, float* __restrict__ out, int B)
{
    __shared__ float zacc[16][REC];
    const int tid = threadIdx.x;
    const int w = tid >> 6, lane = tid & 63;

    if (lane < 51) {
        float acc = 0.f;
        int b = w;
        for (; b + 112 < B; b += 128) {
            acc += ws[(size_t)(b      ) * REC + lane]
                 + ws[(size_t)(b +  16) * REC + lane]
                 + ws[(size_t)(b +  32) * REC + lane]
                 + ws[(size_t)(b +  48) * REC + lane]
                 + ws[(size_t)(b +  64) * REC + lane]
                 + ws[(size_t)(b +  80) * REC + lane]
                 + ws[(size_t)(b +  96) * REC + lane]
                 + ws[(size_t)(b + 112) * REC + lane];
        }
        for (; b < B; b += 16)
            acc += ws[(size_t)b * REC + lane];
        zacc[w][lane] = acc;
    }
    __syncthreads();
    if (tid < NF) {
        float Z = 0.f, S = 0.f;
        #pragma unroll
        for (int h = 0; h < 16; ++h) { Z += zacc[h][tid]; S += zacc[h][50]; }
        out[tid] = Z / S;
    }
}

extern "C" void kernel_launch(void* const* d_in, const int* in_sizes, int n_in,
                              void* d_out, int out_size, void* d_ws, size_t ws_size,
                              hipStream_t stream) {
    const float* query = (const float*)d_in[0];
    const float* ql_w  = (const float*)d_in[1];
    const float* qW    = (const float*)d_in[2];
    float* out = (float*)d_out;
    float* ws  = (float*)d_ws;

    const int T = in_sizes[0] / NF;

    int B = NBLK;
    size_t need = (size_t)B * REC * sizeof(float);
    if (ws_size < need) {
        B = (int)(ws_size / (REC * sizeof(float)));
        if (B < 1) B = 1;
    }

    const int totalGroups = B * 128;
    hipLaunchKernelGGL(attn_pass1, dim3(B), dim3(512), 0, stream,
                       query, ql_w, qW, ws, T, totalGroups);
    hipLaunchKernelGGL(attn_pass2, dim3(1), dim3(1024), 0, stream,
                       ws, out, B);
}